// Round 1
// baseline (377.944 us; speedup 1.0000x reference)
//
#include <hip/hip_runtime.h>
#include <hip/hip_bf16.h>

typedef __attribute__((ext_vector_type(8))) short short8;   // 8 bf16 = one MFMA A/B frag
typedef __attribute__((ext_vector_type(4))) float f32x4;    // MFMA C/D frag

#define BM 64          // edges per tile
#define BLOCK 256      // 4 waves

// LDS layout helpers: logical [row][k] bf16, row stride 256 B,
// byte offset XOR-swizzled by ((row&7)<<4) to break the 16-way bank
// conflict on ds_read_b128 fragment loads (guide §6 G4 / T2).
__device__ __forceinline__ int swz(int row, int k) {
    int byte = row * 256 + k * 2;
    return byte ^ ((row & 7) << 4);
}

__global__ __launch_bounds__(BLOCK, 3) void edge_mlp_kernel(
    const float* __restrict__ src,
    const float* __restrict__ dst,
    const int*   __restrict__ eli,   // [2,E]; width auto-detected (int32 or int64)
    const float* __restrict__ W1,    // [128,128] row-major (k-major rows)
    const float* __restrict__ b1,    // [128]
    const float* __restrict__ W2,    // [128]
    const float* __restrict__ b2,    // [1]
    float* __restrict__ out,         // [E]
    int E)
{
    __shared__ __hip_bfloat16 ldsW[128 * 128]; // W1^T swizzled: [n][k]
    __shared__ __hip_bfloat16 ldsZ[BM * 128];  // [m][k] swizzled
    __shared__ float ldsB1[128];
    __shared__ float ldsW2[128];
    __shared__ int   s_i64;

    const int tid  = threadIdx.x;
    const int lane = tid & 63;
    const int wave = tid >> 6;

    // ---- one-time staging: W1^T (bf16, swizzled), b1, W2, index-width probe
    for (int idx = tid; idx < 128 * 128; idx += BLOCK) {
        int k = idx >> 7, n = idx & 127;           // coalesced read along n
        *(__hip_bfloat16*)((char*)ldsW + swz(n, k)) = __float2bfloat16(W1[idx]);
    }
    if (tid < 128) { ldsB1[tid] = b1[tid]; ldsW2[tid] = W2[tid]; }
    if (tid == 0) {
        // int64 little-endian => odd int32 words are upper halves == 0.
        // For int32 data these words are random node ids (P(all 32 zero) ~ 0).
        int any = 0;
        #pragma unroll
        for (int i = 0; i < 32; ++i) any |= eli[2 * i + 1];
        s_i64 = (any == 0) ? 1 : 0;
    }
    const float bias2 = b2[0];
    const float4* src4 = (const float4*)src;
    const float4* dst4 = (const float4*)dst;

    const int ntiles = (E + BM - 1) / BM;
    const int rr   = lane & 15;   // MFMA row/col-in-tile index
    const int kgrp = lane >> 4;   // 0..3

    for (int tile = blockIdx.x; tile < ntiles; tile += gridDim.x) {
        __syncthreads();  // ldsZ readers of prev tile done; also fences one-time staging
        const int e0 = tile * BM;

        // ---- stage Z tile: z = src[row]*dst[col], bf16, swizzled
        // 32 lanes per edge (float4 each), 2 edges per wave per step
        const int j = lane & 31;                     // float4 column
        for (int m = wave * 2 + (lane >> 5); m < BM; m += 8) {
            int e = e0 + m;
            if (e < E) {
                int r, c;
                if (s_i64) {
                    const long long* e64 = (const long long*)eli;
                    r = (int)e64[e]; c = (int)e64[E + e];
                } else {
                    r = eli[e]; c = eli[E + e];
                }
                float4 s = src4[r * 32 + j];
                float4 d = dst4[c * 32 + j];
                union { __hip_bfloat16 h[4]; uint2 u; } zz;
                zz.h[0] = __float2bfloat16(s.x * d.x);
                zz.h[1] = __float2bfloat16(s.y * d.y);
                zz.h[2] = __float2bfloat16(s.z * d.z);
                zz.h[3] = __float2bfloat16(s.w * d.w);
                *(uint2*)((char*)ldsZ + swz(m, j * 4)) = zz.u;
            }
        }
        __syncthreads();

        // ---- layer 1: per wave, rows [wave*16, wave*16+16) x all 128 hidden
        short8 afrag[4];
        #pragma unroll
        for (int kk = 0; kk < 4; ++kk) {
            int zr = wave * 16 + rr;
            afrag[kk] = *(const short8*)((const char*)ldsZ + swz(zr, kk * 32 + kgrp * 8));
        }
        f32x4 acc[8];
        #pragma unroll
        for (int t = 0; t < 8; ++t) acc[t] = (f32x4){0.f, 0.f, 0.f, 0.f};
        #pragma unroll
        for (int t = 0; t < 8; ++t) {
            #pragma unroll
            for (int kk = 0; kk < 4; ++kk) {
                int nw = t * 16 + rr;
                short8 bfrag = *(const short8*)((const char*)ldsW + swz(nw, kk * 32 + kgrp * 8));
                acc[t] = __builtin_amdgcn_mfma_f32_16x16x32_bf16(afrag[kk], bfrag, acc[t], 0, 0, 0);
            }
        }

        // ---- epilogue: bias + relu + dot with W2 (fp32), 16-lane reduce
        #pragma unroll
        for (int r = 0; r < 4; ++r) {
            float p = 0.f;
            #pragma unroll
            for (int t = 0; t < 8; ++t) {
                float h = acc[t][r] + ldsB1[t * 16 + rr];   // col = t*16+rr
                h = fmaxf(h, 0.f);
                p += h * ldsW2[t * 16 + rr];
            }
            p += __shfl_xor(p, 1, 64);
            p += __shfl_xor(p, 2, 64);
            p += __shfl_xor(p, 4, 64);
            p += __shfl_xor(p, 8, 64);
            if (rr == 0) {
                int e = e0 + wave * 16 + kgrp * 4 + r;      // row = kgrp*4+r
                if (e < E) out[e] = p + bias2;
            }
        }
    }
}

extern "C" void kernel_launch(void* const* d_in, const int* in_sizes, int n_in,
                              void* d_out, int out_size, void* d_ws, size_t ws_size,
                              hipStream_t stream) {
    const float* src = (const float*)d_in[0];
    const float* dst = (const float*)d_in[1];
    const int*   eli = (const int*)d_in[2];
    const float* W1  = (const float*)d_in[3];
    const float* b1  = (const float*)d_in[4];
    const float* W2  = (const float*)d_in[5];
    const float* b2  = (const float*)d_in[6];
    float* out = (float*)d_out;

    const int E = in_sizes[2] / 2;   // flat count of [2,E] (dtype-independent)
    const int ntiles = (E + BM - 1) / BM;
    int grid = ntiles < 2048 ? ntiles : 2048;

    edge_mlp_kernel<<<dim3(grid), dim3(BLOCK), 0, stream>>>(
        src, dst, eli, W1, b1, W2, b2, out, E);
}